// Round 13
// baseline (87.347 us; speedup 1.0000x reference)
//
#include <hip/hip_runtime.h>
#include <hip/hip_bf16.h>
#include <cstddef>
#include <cstdint>

#define EPSV 1e-3f
#define LOG2E 1.4426950408889634f

using f32x4 = __attribute__((ext_vector_type(4))) float;

#if defined(__has_builtin)
#  if __has_builtin(__builtin_amdgcn_exp2f)
#    define EXP2F(v) __builtin_amdgcn_exp2f(v)
#  else
#    define EXP2F(v) exp2f(v)
#  endif
#else
#  define EXP2F(v) exp2f(v)
#endif

// 8-byte fp8 fragment (8 e4m3 values = 2 VGPRs)
union F8 { uint2 v; long long ll; };

// ---------------------------------------------------------------------------
// Kernel 1: projections (unchanged from R12). 512 blocks x 32 pixels.
// theta/phi: [pix][32] fp8 e4m3 (theta pre-scaled by log2e). g CHUNK-MAJOR
// pre-shuffled: gpack[b][chunk=key>>5][d][32] fp8, within-chunk position
// kappa(h,i) = i<4 ? 4h+i : 16+4h+(i-4)  -> PV kmap-agnostic AND the attn
// G-fragment load is contiguous across lanes (512 B/instruction).
// ---------------------------------------------------------------------------
__global__ __launch_bounds__(256) void proj_kernel(
    const float* __restrict__ x,
    const float* __restrict__ gW, const float* __restrict__ gbias,
    const float* __restrict__ pW, const float* __restrict__ pbias,
    const float* __restrict__ tW, const float* __restrict__ tbias,
    uint8_t* __restrict__ thetab,
    uint8_t* __restrict__ phib,
    uint8_t* __restrict__ gshuf)
{
    __shared__ float lx[32*65];
    __shared__ __align__(16) float lw96[64*96];
    __shared__ float lbias[96];
    const int tid = threadIdx.x;
    const int pix0 = blockIdx.x * 32;

    #pragma unroll
    for (int j = 0; j < 8; ++j) {
        int idx = tid + 256*j;
        lx[(idx >> 6)*65 + (idx & 63)] = x[(size_t)pix0*64 + idx];
    }
    #pragma unroll
    for (int j = 0; j < 8; ++j) {
        int idx = tid + 256*j;
        int c = idx >> 5, o = idx & 31;
        lw96[c*96 + o]      = tW[idx];
        lw96[c*96 + 32 + o] = pW[idx];
        lw96[c*96 + 64 + o] = gW[idx];
    }
    if (tid < 32) { lbias[tid] = tbias[tid]; lbias[32+tid] = pbias[tid]; lbias[64+tid] = gbias[tid]; }
    __syncthreads();

    const int p  = tid & 31;
    const int og = tid >> 5;
    const int obase = og*12;
    float acc[12];
    #pragma unroll
    for (int j = 0; j < 12; ++j) acc[j] = 0.f;
    for (int c = 0; c < 64; ++c) {
        float xc = lx[p*65 + c];
        const float4* wp = (const float4*)&lw96[c*96 + obase];
        float4 w0 = wp[0], w1 = wp[1], w2 = wp[2];
        acc[0]  += xc * w0.x; acc[1]  += xc * w0.y; acc[2]  += xc * w0.z; acc[3]  += xc * w0.w;
        acc[4]  += xc * w1.x; acc[5]  += xc * w1.y; acc[6]  += xc * w1.z; acc[7]  += xc * w1.w;
        acc[8]  += xc * w2.x; acc[9]  += xc * w2.y; acc[10] += xc * w2.z; acc[11] += xc * w2.w;
    }
    const int pix = pix0 + p;
    const int b = pix >> 12;
    const int n = pix & 4095;
    const int chunk = n >> 5;
    const int loc = n & 31;
    const int t  = (loc >> 4) & 1;
    const int hh = (loc >> 2) & 3;
    const int jj = loc & 3;
    const int within = 8*hh + jj + 4*t;          // kappa position inside chunk
    #pragma unroll
    for (int j = 0; j < 12; ++j) {
        int o = obase + j;
        float v = acc[j] + lbias[o];
        float vs = (o < 32) ? v * LOG2E : v;
        int pk = __builtin_amdgcn_cvt_pk_fp8_f32(vs, vs, 0, false);
        uint8_t bv = (uint8_t)(pk & 0xFF);
        if (o < 32)       thetab[(size_t)pix*32 + o] = bv;
        else if (o < 64)  phib[(size_t)pix*32 + (o-32)] = bv;
        else              gshuf[((size_t)(b*128 + chunk)*32 + (o-64))*32 + within] = bv;
    }
}

// ---------------------------------------------------------------------------
// Kernel 2: fused flash-attention + output conv + BN partial stats.
// EXACT R12 structure (proven 38.4us total) with ONE change:
// __launch_bounds__(1024, 8) -> VGPR capped at 64 -> 2 blocks/CU ->
// 32 waves/CU = 8 waves/SIMD (was 4). fp8 fragments (2 VGPRs each) are what
// makes the 64-VGPR fit plausible. LDS 76.3KB x 2 = 152.5KB <= 160KB.
// ---------------------------------------------------------------------------
__global__ __launch_bounds__(1024, 8) void attn_kernel(
    const uint8_t* __restrict__ thetab,
    const uint8_t* __restrict__ phib,
    const uint8_t* __restrict__ gshuf,
    const float* __restrict__ wW, const float* __restrict__ wb,
    float* __restrict__ out, float* __restrict__ stats)
{
    __shared__ float yl[16][32][33];   // 67.6 KB
    __shared__ float lred[16][32];
    __shared__ float lwW[2048];
    __shared__ float lwb[64];
    const int tid  = threadIdx.x;
    const int wave = tid >> 6;
    const int lane = tid & 63;
    const int h = lane >> 4;
    const int r = lane & 15;
    const int blk = blockIdx.x;
    const int b = blk >> 6;            // 64 q-blocks per batch
    const int q0 = (blk & 63) * 64;
    const int qh = wave >> 3;          // query half 0/1
    const int kq = wave & 7;           // key octant
    const int qbase = q0 + qh*32;
    const size_t base = (size_t)b * 4096;

    #pragma unroll
    for (int j = 0; j < 2; ++j) lwW[tid + 1024*j] = wW[tid + 1024*j];
    if (tid < 64) lwb[tid] = wb[tid];

    F8 qaA, qaB;
    qaA.v = *(const uint2*)(thetab + (base + qbase + r)*32 + h*8);
    qaB.v = *(const uint2*)(thetab + (base + qbase + 16 + r)*32 + h*8);
    const uint8_t* phiB = phib  + base*32;
    const uint8_t* gB   = gshuf + (size_t)b*131072;   // b*128 chunks * 1024 B

    f32x4 y0A = {0,0,0,0}, y1A = {0,0,0,0};
    f32x4 y0B = {0,0,0,0}, y1B = {0,0,0,0};
    float lsA = 0.f, lsB = 0.f;

    const int kbeg = kq * 512;
    const int kend = kbeg + 512;
    F8 ka, kb, g0, g1;
    ka.v = *(const uint2*)(phiB + (size_t)(kbeg + r)*32 + h*8);
    kb.v = *(const uint2*)(phiB + (size_t)(kbeg + 16 + r)*32 + h*8);
    g0.v = *(const uint2*)(gB + (size_t)(kbeg >> 5)*1024 + r*32 + 8*h);
    g1.v = *(const uint2*)(gB + (size_t)(kbeg >> 5)*1024 + (16 + r)*32 + 8*h);

    for (int kk = kbeg; kk < kend; kk += 32) {
        const int nk = (kk + 32 < kend) ? (kk + 32) : kbeg;   // depth-1 prefetch
        F8 ka2, kb2, g02, g12;
        ka2.v = *(const uint2*)(phiB + (size_t)(nk + r)*32 + h*8);
        kb2.v = *(const uint2*)(phiB + (size_t)(nk + 16 + r)*32 + h*8);
        g02.v = *(const uint2*)(gB + (size_t)(nk >> 5)*1024 + r*32 + 8*h);
        g12.v = *(const uint2*)(gB + (size_t)(nk >> 5)*1024 + (16 + r)*32 + 8*h);

        f32x4 z = {0,0,0,0};
        f32x4 s0A = __builtin_amdgcn_mfma_f32_16x16x32_fp8_fp8(ka.ll, qaA.ll, z, 0, 0, 0);
        f32x4 s1A = __builtin_amdgcn_mfma_f32_16x16x32_fp8_fp8(kb.ll, qaA.ll, z, 0, 0, 0);
        f32x4 s0B = __builtin_amdgcn_mfma_f32_16x16x32_fp8_fp8(ka.ll, qaB.ll, z, 0, 0, 0);
        f32x4 s1B = __builtin_amdgcn_mfma_f32_16x16x32_fp8_fp8(kb.ll, qaB.ll, z, 0, 0, 0);

        float pA0 = EXP2F(s0A[0]), pA1 = EXP2F(s0A[1]), pA2 = EXP2F(s0A[2]), pA3 = EXP2F(s0A[3]);
        float pA4 = EXP2F(s1A[0]), pA5 = EXP2F(s1A[1]), pA6 = EXP2F(s1A[2]), pA7 = EXP2F(s1A[3]);
        float pB0 = EXP2F(s0B[0]), pB1 = EXP2F(s0B[1]), pB2 = EXP2F(s0B[2]), pB3 = EXP2F(s0B[3]);
        float pB4 = EXP2F(s1B[0]), pB5 = EXP2F(s1B[1]), pB6 = EXP2F(s1B[2]), pB7 = EXP2F(s1B[3]);
        lsA += ((pA0+pA1)+(pA2+pA3)) + ((pA4+pA5)+(pA6+pA7));
        lsB += ((pB0+pB1)+(pB2+pB3)) + ((pB4+pB5)+(pB6+pB7));

        // pack P to fp8 in the SAME key order as gshuf's bake:
        // slots 0..7 = keys [4h..4h+3, 16+4h..16+4h+3]
        F8 paA, paB;
        {
            int lo = __builtin_amdgcn_cvt_pk_fp8_f32(pA0, pA1, 0, false);
            lo     = __builtin_amdgcn_cvt_pk_fp8_f32(pA2, pA3, lo, true);
            int hi = __builtin_amdgcn_cvt_pk_fp8_f32(pA4, pA5, 0, false);
            hi     = __builtin_amdgcn_cvt_pk_fp8_f32(pA6, pA7, hi, true);
            paA.v.x = (uint32_t)lo; paA.v.y = (uint32_t)hi;
            lo = __builtin_amdgcn_cvt_pk_fp8_f32(pB0, pB1, 0, false);
            lo = __builtin_amdgcn_cvt_pk_fp8_f32(pB2, pB3, lo, true);
            hi = __builtin_amdgcn_cvt_pk_fp8_f32(pB4, pB5, 0, false);
            hi = __builtin_amdgcn_cvt_pk_fp8_f32(pB6, pB7, hi, true);
            paB.v.x = (uint32_t)lo; paB.v.y = (uint32_t)hi;
        }

        y0A = __builtin_amdgcn_mfma_f32_16x16x32_fp8_fp8(paA.ll, g0.ll, y0A, 0, 0, 0);
        y1A = __builtin_amdgcn_mfma_f32_16x16x32_fp8_fp8(paA.ll, g1.ll, y1A, 0, 0, 0);
        y0B = __builtin_amdgcn_mfma_f32_16x16x32_fp8_fp8(paB.ll, g0.ll, y0B, 0, 0, 0);
        y1B = __builtin_amdgcn_mfma_f32_16x16x32_fp8_fp8(paB.ll, g1.ll, y1B, 0, 0, 0);

        ka = ka2; kb = kb2; g0 = g02; g1 = g12;
    }

    lsA += __shfl_xor(lsA, 16); lsA += __shfl_xor(lsA, 32);
    lsB += __shfl_xor(lsB, 16); lsB += __shfl_xor(lsB, 32);

    #pragma unroll
    for (int gi = 0; gi < 4; ++gi) {
        yl[wave][4*h+gi][r]       = y0A[gi];
        yl[wave][4*h+gi][16+r]    = y1A[gi];
        yl[wave][16+4*h+gi][r]    = y0B[gi];
        yl[wave][16+4*h+gi][16+r] = y1B[gi];
    }
    if (lane < 16) { lred[wave][r] = lsA; lred[wave][16+r] = lsB; }
    __syncthreads();

    // Phase B: combine 8 key-octant waves per query half + normalize.
    {
        const int q   = tid >> 4;
        const int d2  = (tid & 15) * 2;
        const int qh2 = q >> 5;
        const int ql  = q & 31;
        float a0=0.f, a1=0.f, lq=0.f;
        #pragma unroll
        for (int w = 0; w < 8; ++w) {
            a0 += yl[qh2*8+w][ql][d2];
            a1 += yl[qh2*8+w][ql][d2+1];
            lq += lred[qh2*8+w][ql];
        }
        float inv = 1.0f / lq;
        yl[qh2*8][ql][d2]   = a0*inv;
        yl[qh2*8][ql][d2+1] = a1*inv;
    }
    __syncthreads();

    // Phase C: w_y = y @ w_W + w_b -> out (pre-BN); channel sum/sumsq.
    {
        const int p   = lane;              // pixel within block (0..63)
        const int cg_ = wave;              // channel group (0..15)
        float acc[4];
        #pragma unroll
        for (int j = 0; j < 4; ++j) acc[j] = lwb[cg_*4 + j];
        for (int d = 0; d < 32; ++d) {
            float yv = yl[(p >> 5)*8][p & 31][d];
            #pragma unroll
            for (int j = 0; j < 4; ++j) acc[j] += yv * lwW[d*64 + cg_*4 + j];
        }
        *(float4*)(out + (size_t)(base + q0 + p)*64 + cg_*4) = *(float4*)&acc[0];

        float s1[4], s2[4];
        #pragma unroll
        for (int j = 0; j < 4; ++j) { s1[j] = acc[j]; s2[j] = acc[j]*acc[j]; }
        #pragma unroll
        for (int m = 1; m <= 32; m <<= 1) {
            #pragma unroll
            for (int j = 0; j < 4; ++j) {
                s1[j] += __shfl_xor(s1[j], m);
                s2[j] += __shfl_xor(s2[j], m);
            }
        }
        if (lane == 0) {                    // transposed: stats[stat_row][block]
            #pragma unroll
            for (int j = 0; j < 4; ++j) {
                stats[(size_t)(cg_*4 + j)*256 + blk]        = s1[j];
                stats[(size_t)(64 + cg_*4 + j)*256 + blk]   = s2[j];
            }
        }
    }
}

// ---------------------------------------------------------------------------
// Kernel 3: fused BN-finalize + apply (unchanged from R12).
// ---------------------------------------------------------------------------
__global__ __launch_bounds__(256) void apply_kernel(
    const float* __restrict__ stats,
    const float* __restrict__ gamma,
    const float* __restrict__ beta,
    const float* __restrict__ x,
    float* __restrict__ out)
{
    __shared__ float sums1[64];
    __shared__ float sums2[64];
    __shared__ __align__(16) float params[128];
    const int tid = threadIdx.x;
    {
        const int c = tid >> 2;        // 0..63
        const int part = tid & 3;      // 0..3 -> blocks part*64..+63
        const float4* st4 = (const float4*)stats;
        float s1 = 0.f, s2 = 0.f;
        #pragma unroll
        for (int j = 0; j < 16; ++j) {
            float4 v = st4[c*64 + part*16 + j];
            s1 += (v.x + v.y) + (v.z + v.w);
        }
        #pragma unroll
        for (int j = 0; j < 16; ++j) {
            float4 v = st4[(64 + c)*64 + part*16 + j];
            s2 += (v.x + v.y) + (v.z + v.w);
        }
        s1 += __shfl_xor(s1, 1); s1 += __shfl_xor(s1, 2);
        s2 += __shfl_xor(s2, 1); s2 += __shfl_xor(s2, 2);
        if (part == 0) { sums1[c] = s1; sums2[c] = s2; }
    }
    __syncthreads();
    if (tid < 64) {
        float mean = sums1[tid] * (1.0f/16384.0f);
        float var  = sums2[tid] * (1.0f/16384.0f) - mean*mean;
        float sc = gamma[tid] * rsqrtf(var + EPSV);
        params[tid]      = sc;
        params[64 + tid] = beta[tid] - mean*sc;
    }
    __syncthreads();

    const float4* x4 = (const float4*)x;
    float4* o4 = (float4*)out;
    #pragma unroll
    for (int j = 0; j < 4; ++j) {
        int i4 = blockIdx.x*1024 + tid + 256*j;   // 262144 float4s total
        int cb = (i4 & 15) * 4;
        float4 v  = o4[i4];
        float4 xv = x4[i4];
        float4 sc = *(const float4*)&params[cb];
        float4 sh = *(const float4*)&params[64 + cb];
        float4 rr;
        rr.x = xv.x + sc.x*v.x + sh.x;
        rr.y = xv.y + sc.y*v.y + sh.y;
        rr.z = xv.z + sc.z*v.z + sh.z;
        rr.w = xv.w + sc.w*v.w + sh.w;
        o4[i4] = rr;
    }
}

// ---------------------------------------------------------------------------
extern "C" void kernel_launch(void* const* d_in, const int* in_sizes, int n_in,
                              void* d_out, int out_size, void* d_ws, size_t ws_size,
                              hipStream_t stream)
{
    const float* x     = (const float*)d_in[0];
    const float* gW    = (const float*)d_in[1];
    const float* gb    = (const float*)d_in[2];
    const float* pW    = (const float*)d_in[3];
    const float* pb    = (const float*)d_in[4];
    const float* tW    = (const float*)d_in[5];
    const float* tb    = (const float*)d_in[6];
    const float* wW    = (const float*)d_in[7];
    const float* wb    = (const float*)d_in[8];
    const float* gamma = (const float*)d_in[9];
    const float* beta  = (const float*)d_in[10];
    float* out = (float*)d_out;

    char* w = (char*)d_ws;
    uint8_t* thetab = (uint8_t*)(w);                               // 512 KB
    uint8_t* phib   = (uint8_t*)(w + (1u<<19));                    // 512 KB
    uint8_t* gshuf  = (uint8_t*)(w + (2u<<19));                    // 512 KB
    float* stats    = (float*)(w + (3u<<19));                      // 128 KB

    proj_kernel<<<512, 256, 0, stream>>>(x, gW, gb, pW, pb, tW, tb, thetab, phib, gshuf);
    attn_kernel<<<256, 1024, 0, stream>>>(thetab, phib, gshuf, wW, wb, out, stats);
    apply_kernel<<<256, 256, 0, stream>>>(stats, gamma, beta, x, out);
}

// Round 14
// 37.085 us; speedup vs baseline: 2.3553x; 2.3553x over previous
//
#include <hip/hip_runtime.h>
#include <hip/hip_bf16.h>
#include <cstddef>
#include <cstdint>

#define EPSV 1e-3f
#define LOG2E 1.4426950408889634f

using f32x4 = __attribute__((ext_vector_type(4))) float;

#if defined(__has_builtin)
#  if __has_builtin(__builtin_amdgcn_exp2f)
#    define EXP2F(v) __builtin_amdgcn_exp2f(v)
#  else
#    define EXP2F(v) exp2f(v)
#  endif
#else
#  define EXP2F(v) exp2f(v)
#endif

// 8-byte fp8 fragment (8 e4m3 values = 2 VGPRs)
union F8 { uint2 v; long long ll; };

// ---------------------------------------------------------------------------
// Kernel 1: projections (unchanged from R12). 512 blocks x 32 pixels.
// theta/phi: [pix][32] fp8 e4m3 (theta pre-scaled by log2e). g CHUNK-MAJOR
// pre-shuffled: gpack[b][chunk=key>>5][d][32] fp8, within-chunk position
// kappa(h,i) = i<4 ? 4h+i : 16+4h+(i-4)  -> PV kmap-agnostic AND the attn
// G-fragment load is contiguous across lanes (512 B/instruction).
// ---------------------------------------------------------------------------
__global__ __launch_bounds__(256) void proj_kernel(
    const float* __restrict__ x,
    const float* __restrict__ gW, const float* __restrict__ gbias,
    const float* __restrict__ pW, const float* __restrict__ pbias,
    const float* __restrict__ tW, const float* __restrict__ tbias,
    uint8_t* __restrict__ thetab,
    uint8_t* __restrict__ phib,
    uint8_t* __restrict__ gshuf)
{
    __shared__ float lx[32*65];
    __shared__ __align__(16) float lw96[64*96];
    __shared__ float lbias[96];
    const int tid = threadIdx.x;
    const int pix0 = blockIdx.x * 32;

    #pragma unroll
    for (int j = 0; j < 8; ++j) {
        int idx = tid + 256*j;
        lx[(idx >> 6)*65 + (idx & 63)] = x[(size_t)pix0*64 + idx];
    }
    #pragma unroll
    for (int j = 0; j < 8; ++j) {
        int idx = tid + 256*j;
        int c = idx >> 5, o = idx & 31;
        lw96[c*96 + o]      = tW[idx];
        lw96[c*96 + 32 + o] = pW[idx];
        lw96[c*96 + 64 + o] = gW[idx];
    }
    if (tid < 32) { lbias[tid] = tbias[tid]; lbias[32+tid] = pbias[tid]; lbias[64+tid] = gbias[tid]; }
    __syncthreads();

    const int p  = tid & 31;
    const int og = tid >> 5;
    const int obase = og*12;
    float acc[12];
    #pragma unroll
    for (int j = 0; j < 12; ++j) acc[j] = 0.f;
    for (int c = 0; c < 64; ++c) {
        float xc = lx[p*65 + c];
        const float4* wp = (const float4*)&lw96[c*96 + obase];
        float4 w0 = wp[0], w1 = wp[1], w2 = wp[2];
        acc[0]  += xc * w0.x; acc[1]  += xc * w0.y; acc[2]  += xc * w0.z; acc[3]  += xc * w0.w;
        acc[4]  += xc * w1.x; acc[5]  += xc * w1.y; acc[6]  += xc * w1.z; acc[7]  += xc * w1.w;
        acc[8]  += xc * w2.x; acc[9]  += xc * w2.y; acc[10] += xc * w2.z; acc[11] += xc * w2.w;
    }
    const int pix = pix0 + p;
    const int b = pix >> 12;
    const int n = pix & 4095;
    const int chunk = n >> 5;
    const int loc = n & 31;
    const int t  = (loc >> 4) & 1;
    const int hh = (loc >> 2) & 3;
    const int jj = loc & 3;
    const int within = 8*hh + jj + 4*t;          // kappa position inside chunk
    #pragma unroll
    for (int j = 0; j < 12; ++j) {
        int o = obase + j;
        float v = acc[j] + lbias[o];
        float vs = (o < 32) ? v * LOG2E : v;
        int pk = __builtin_amdgcn_cvt_pk_fp8_f32(vs, vs, 0, false);
        uint8_t bv = (uint8_t)(pk & 0xFF);
        if (o < 32)       thetab[(size_t)pix*32 + o] = bv;
        else if (o < 64)  phib[(size_t)pix*32 + (o-32)] = bv;
        else              gshuf[((size_t)(b*128 + chunk)*32 + (o-64))*32 + within] = bv;
    }
}

// ---------------------------------------------------------------------------
// Kernel 2: fused flash-attention + output conv + BN partial stats.
// R12 structure (proven 38.4us) at __launch_bounds__(1024,4) [R13's (,8)
// forced VGPR=32 -> 154MB scratch spill -> 77us; reverted].
// NEW: software-pipelined compute chain — PV lags QK by one chunk:
//   iter t: loads(t+1) | PV(t-1) [uses pa packed last iter] | QK(t)+exp+pack
// so PV MFMAs are independent of this iteration's exp chain and co-issue
// with QK on the matrix pipe; the serial QK->exp->pack->PV chain now spans
// two iterations instead of one. Extra state: 1 more G staging set + packed
// P carry (~+14 VGPRs, fits 128 cap).
// ---------------------------------------------------------------------------
__global__ __launch_bounds__(1024, 4) void attn_kernel(
    const uint8_t* __restrict__ thetab,
    const uint8_t* __restrict__ phib,
    const uint8_t* __restrict__ gshuf,
    const float* __restrict__ wW, const float* __restrict__ wb,
    float* __restrict__ out, float* __restrict__ stats)
{
    __shared__ float yl[16][32][33];   // 67.6 KB
    __shared__ float lred[16][32];
    __shared__ float lwW[2048];
    __shared__ float lwb[64];
    const int tid  = threadIdx.x;
    const int wave = tid >> 6;
    const int lane = tid & 63;
    const int h = lane >> 4;
    const int r = lane & 15;
    const int blk = blockIdx.x;
    const int b = blk >> 6;            // 64 q-blocks per batch
    const int q0 = (blk & 63) * 64;
    const int qh = wave >> 3;          // query half 0/1
    const int kq = wave & 7;           // key octant
    const int qbase = q0 + qh*32;
    const size_t base = (size_t)b * 4096;

    #pragma unroll
    for (int j = 0; j < 2; ++j) lwW[tid + 1024*j] = wW[tid + 1024*j];
    if (tid < 64) lwb[tid] = wb[tid];

    F8 qaA, qaB;
    qaA.v = *(const uint2*)(thetab + (base + qbase + r)*32 + h*8);
    qaB.v = *(const uint2*)(thetab + (base + qbase + 16 + r)*32 + h*8);
    const uint8_t* phiB = phib  + base*32;
    const uint8_t* gB   = gshuf + (size_t)b*131072;   // b*128 chunks * 1024 B

    f32x4 y0A = {0,0,0,0}, y1A = {0,0,0,0};
    f32x4 y0B = {0,0,0,0}, y1B = {0,0,0,0};
    float lsA = 0.f, lsB = 0.f;

    const int kbeg = kq * 512;

    // QK(chunk) + exp + pack -> pa (key order matches gshuf bake:
    // slots 0..7 = keys [4h..4h+3, 16+4h..16+4h+3])
    auto QKEXP = [&](const F8& ka_, const F8& kb_, F8& pA_, F8& pB_) {
        f32x4 z = {0,0,0,0};
        f32x4 s0A = __builtin_amdgcn_mfma_f32_16x16x32_fp8_fp8(ka_.ll, qaA.ll, z, 0, 0, 0);
        f32x4 s1A = __builtin_amdgcn_mfma_f32_16x16x32_fp8_fp8(kb_.ll, qaA.ll, z, 0, 0, 0);
        f32x4 s0B = __builtin_amdgcn_mfma_f32_16x16x32_fp8_fp8(ka_.ll, qaB.ll, z, 0, 0, 0);
        f32x4 s1B = __builtin_amdgcn_mfma_f32_16x16x32_fp8_fp8(kb_.ll, qaB.ll, z, 0, 0, 0);

        float pA0 = EXP2F(s0A[0]), pA1 = EXP2F(s0A[1]), pA2 = EXP2F(s0A[2]), pA3 = EXP2F(s0A[3]);
        float pA4 = EXP2F(s1A[0]), pA5 = EXP2F(s1A[1]), pA6 = EXP2F(s1A[2]), pA7 = EXP2F(s1A[3]);
        float pB0 = EXP2F(s0B[0]), pB1 = EXP2F(s0B[1]), pB2 = EXP2F(s0B[2]), pB3 = EXP2F(s0B[3]);
        float pB4 = EXP2F(s1B[0]), pB5 = EXP2F(s1B[1]), pB6 = EXP2F(s1B[2]), pB7 = EXP2F(s1B[3]);
        lsA += ((pA0+pA1)+(pA2+pA3)) + ((pA4+pA5)+(pA6+pA7));
        lsB += ((pB0+pB1)+(pB2+pB3)) + ((pB4+pB5)+(pB6+pB7));

        int lo = __builtin_amdgcn_cvt_pk_fp8_f32(pA0, pA1, 0, false);
        lo     = __builtin_amdgcn_cvt_pk_fp8_f32(pA2, pA3, lo, true);
        int hi = __builtin_amdgcn_cvt_pk_fp8_f32(pA4, pA5, 0, false);
        hi     = __builtin_amdgcn_cvt_pk_fp8_f32(pA6, pA7, hi, true);
        pA_.v.x = (uint32_t)lo; pA_.v.y = (uint32_t)hi;
        lo = __builtin_amdgcn_cvt_pk_fp8_f32(pB0, pB1, 0, false);
        lo = __builtin_amdgcn_cvt_pk_fp8_f32(pB2, pB3, lo, true);
        hi = __builtin_amdgcn_cvt_pk_fp8_f32(pB4, pB5, 0, false);
        hi = __builtin_amdgcn_cvt_pk_fp8_f32(pB6, pB7, hi, true);
        pB_.v.x = (uint32_t)lo; pB_.v.y = (uint32_t)hi;
    };

    // staging: kaC/kbC = K frags for the chunk whose QK runs this iter;
    // g*P = G for the chunk whose PV runs this iter; g*C = one chunk ahead.
    F8 kaC, kbC, kaN, kbN;
    F8 g0P, g1P, g0C, g1C, g0N, g1N;
    kaC.v = *(const uint2*)(phiB + (size_t)(kbeg + r)*32 + h*8);
    kbC.v = *(const uint2*)(phiB + (size_t)(kbeg + 16 + r)*32 + h*8);
    g0P.v = *(const uint2*)(gB + (size_t)(kbeg >> 5)*1024 + r*32 + 8*h);
    g1P.v = *(const uint2*)(gB + (size_t)(kbeg >> 5)*1024 + (16 + r)*32 + 8*h);
    {
        const int c1 = kbeg + 32;
        kaN.v = *(const uint2*)(phiB + (size_t)(c1 + r)*32 + h*8);
        kbN.v = *(const uint2*)(phiB + (size_t)(c1 + 16 + r)*32 + h*8);
        g0C.v = *(const uint2*)(gB + (size_t)(c1 >> 5)*1024 + r*32 + 8*h);
        g1C.v = *(const uint2*)(gB + (size_t)(c1 >> 5)*1024 + (16 + r)*32 + 8*h);
    }

    F8 paA0, paB0;
    QKEXP(kaC, kbC, paA0, paB0);       // chunk 0
    kaC = kaN; kbC = kbN;              // kaC now holds k(1)

    for (int t = 1; t < 16; ++t) {
        const int nc = (t + 1 < 16) ? kbeg + (t + 1)*32 : kbeg;  // dummy wrap at end
        kaN.v = *(const uint2*)(phiB + (size_t)(nc + r)*32 + h*8);
        kbN.v = *(const uint2*)(phiB + (size_t)(nc + 16 + r)*32 + h*8);
        g0N.v = *(const uint2*)(gB + (size_t)(nc >> 5)*1024 + r*32 + 8*h);
        g1N.v = *(const uint2*)(gB + (size_t)(nc >> 5)*1024 + (16 + r)*32 + 8*h);

        // PV for chunk t-1 (independent of this iteration's QK/exp chain)
        y0A = __builtin_amdgcn_mfma_f32_16x16x32_fp8_fp8(paA0.ll, g0P.ll, y0A, 0, 0, 0);
        y1A = __builtin_amdgcn_mfma_f32_16x16x32_fp8_fp8(paA0.ll, g1P.ll, y1A, 0, 0, 0);
        y0B = __builtin_amdgcn_mfma_f32_16x16x32_fp8_fp8(paB0.ll, g0P.ll, y0B, 0, 0, 0);
        y1B = __builtin_amdgcn_mfma_f32_16x16x32_fp8_fp8(paB0.ll, g1P.ll, y1B, 0, 0, 0);

        // QK + exp + pack for chunk t (overwrites pa carry)
        QKEXP(kaC, kbC, paA0, paB0);

        kaC = kaN; kbC = kbN;
        g0P = g0C; g1P = g1C;
        g0C = g0N; g1C = g1N;
    }
    // epilogue: PV for chunk 15
    y0A = __builtin_amdgcn_mfma_f32_16x16x32_fp8_fp8(paA0.ll, g0P.ll, y0A, 0, 0, 0);
    y1A = __builtin_amdgcn_mfma_f32_16x16x32_fp8_fp8(paA0.ll, g1P.ll, y1A, 0, 0, 0);
    y0B = __builtin_amdgcn_mfma_f32_16x16x32_fp8_fp8(paB0.ll, g0P.ll, y0B, 0, 0, 0);
    y1B = __builtin_amdgcn_mfma_f32_16x16x32_fp8_fp8(paB0.ll, g1P.ll, y1B, 0, 0, 0);

    lsA += __shfl_xor(lsA, 16); lsA += __shfl_xor(lsA, 32);
    lsB += __shfl_xor(lsB, 16); lsB += __shfl_xor(lsB, 32);

    #pragma unroll
    for (int gi = 0; gi < 4; ++gi) {
        yl[wave][4*h+gi][r]       = y0A[gi];
        yl[wave][4*h+gi][16+r]    = y1A[gi];
        yl[wave][16+4*h+gi][r]    = y0B[gi];
        yl[wave][16+4*h+gi][16+r] = y1B[gi];
    }
    if (lane < 16) { lred[wave][r] = lsA; lred[wave][16+r] = lsB; }
    __syncthreads();

    // Phase B: combine 8 key-octant waves per query half + normalize.
    {
        const int q   = tid >> 4;
        const int d2  = (tid & 15) * 2;
        const int qh2 = q >> 5;
        const int ql  = q & 31;
        float a0=0.f, a1=0.f, lq=0.f;
        #pragma unroll
        for (int w = 0; w < 8; ++w) {
            a0 += yl[qh2*8+w][ql][d2];
            a1 += yl[qh2*8+w][ql][d2+1];
            lq += lred[qh2*8+w][ql];
        }
        float inv = 1.0f / lq;
        yl[qh2*8][ql][d2]   = a0*inv;
        yl[qh2*8][ql][d2+1] = a1*inv;
    }
    __syncthreads();

    // Phase C: w_y = y @ w_W + w_b -> out (pre-BN); channel sum/sumsq.
    {
        const int p   = lane;              // pixel within block (0..63)
        const int cg_ = wave;              // channel group (0..15)
        float acc[4];
        #pragma unroll
        for (int j = 0; j < 4; ++j) acc[j] = lwb[cg_*4 + j];
        for (int d = 0; d < 32; ++d) {
            float yv = yl[(p >> 5)*8][p & 31][d];
            #pragma unroll
            for (int j = 0; j < 4; ++j) acc[j] += yv * lwW[d*64 + cg_*4 + j];
        }
        *(float4*)(out + (size_t)(base + q0 + p)*64 + cg_*4) = *(float4*)&acc[0];

        float s1[4], s2[4];
        #pragma unroll
        for (int j = 0; j < 4; ++j) { s1[j] = acc[j]; s2[j] = acc[j]*acc[j]; }
        #pragma unroll
        for (int m = 1; m <= 32; m <<= 1) {
            #pragma unroll
            for (int j = 0; j < 4; ++j) {
                s1[j] += __shfl_xor(s1[j], m);
                s2[j] += __shfl_xor(s2[j], m);
            }
        }
        if (lane == 0) {                    // transposed: stats[stat_row][block]
            #pragma unroll
            for (int j = 0; j < 4; ++j) {
                stats[(size_t)(cg_*4 + j)*256 + blk]        = s1[j];
                stats[(size_t)(64 + cg_*4 + j)*256 + blk]   = s2[j];
            }
        }
    }
}

// ---------------------------------------------------------------------------
// Kernel 3: fused BN-finalize + apply (unchanged from R12).
// ---------------------------------------------------------------------------
__global__ __launch_bounds__(256) void apply_kernel(
    const float* __restrict__ stats,
    const float* __restrict__ gamma,
    const float* __restrict__ beta,
    const float* __restrict__ x,
    float* __restrict__ out)
{
    __shared__ float sums1[64];
    __shared__ float sums2[64];
    __shared__ __align__(16) float params[128];
    const int tid = threadIdx.x;
    {
        const int c = tid >> 2;        // 0..63
        const int part = tid & 3;      // 0..3 -> blocks part*64..+63
        const float4* st4 = (const float4*)stats;
        float s1 = 0.f, s2 = 0.f;
        #pragma unroll
        for (int j = 0; j < 16; ++j) {
            float4 v = st4[c*64 + part*16 + j];
            s1 += (v.x + v.y) + (v.z + v.w);
        }
        #pragma unroll
        for (int j = 0; j < 16; ++j) {
            float4 v = st4[(64 + c)*64 + part*16 + j];
            s2 += (v.x + v.y) + (v.z + v.w);
        }
        s1 += __shfl_xor(s1, 1); s1 += __shfl_xor(s1, 2);
        s2 += __shfl_xor(s2, 1); s2 += __shfl_xor(s2, 2);
        if (part == 0) { sums1[c] = s1; sums2[c] = s2; }
    }
    __syncthreads();
    if (tid < 64) {
        float mean = sums1[tid] * (1.0f/16384.0f);
        float var  = sums2[tid] * (1.0f/16384.0f) - mean*mean;
        float sc = gamma[tid] * rsqrtf(var + EPSV);
        params[tid]      = sc;
        params[64 + tid] = beta[tid] - mean*sc;
    }
    __syncthreads();

    const float4* x4 = (const float4*)x;
    float4* o4 = (float4*)out;
    #pragma unroll
    for (int j = 0; j < 4; ++j) {
        int i4 = blockIdx.x*1024 + tid + 256*j;   // 262144 float4s total
        int cb = (i4 & 15) * 4;
        float4 v  = o4[i4];
        float4 xv = x4[i4];
        float4 sc = *(const float4*)&params[cb];
        float4 sh = *(const float4*)&params[64 + cb];
        float4 rr;
        rr.x = xv.x + sc.x*v.x + sh.x;
        rr.y = xv.y + sc.y*v.y + sh.y;
        rr.z = xv.z + sc.z*v.z + sh.z;
        rr.w = xv.w + sc.w*v.w + sh.w;
        o4[i4] = rr;
    }
}

// ---------------------------------------------------------------------------
extern "C" void kernel_launch(void* const* d_in, const int* in_sizes, int n_in,
                              void* d_out, int out_size, void* d_ws, size_t ws_size,
                              hipStream_t stream)
{
    const float* x     = (const float*)d_in[0];
    const float* gW    = (const float*)d_in[1];
    const float* gb    = (const float*)d_in[2];
    const float* pW    = (const float*)d_in[3];
    const float* pb    = (const float*)d_in[4];
    const float* tW    = (const float*)d_in[5];
    const float* tb    = (const float*)d_in[6];
    const float* wW    = (const float*)d_in[7];
    const float* wb    = (const float*)d_in[8];
    const float* gamma = (const float*)d_in[9];
    const float* beta  = (const float*)d_in[10];
    float* out = (float*)d_out;

    char* w = (char*)d_ws;
    uint8_t* thetab = (uint8_t*)(w);                               // 512 KB
    uint8_t* phib   = (uint8_t*)(w + (1u<<19));                    // 512 KB
    uint8_t* gshuf  = (uint8_t*)(w + (2u<<19));                    // 512 KB
    float* stats    = (float*)(w + (3u<<19));                      // 128 KB

    proj_kernel<<<512, 256, 0, stream>>>(x, gW, gb, pW, pb, tW, tb, thetab, phib, gshuf);
    attn_kernel<<<256, 1024, 0, stream>>>(thetab, phib, gshuf, wW, wb, out, stats);
    apply_kernel<<<256, 256, 0, stream>>>(stats, gamma, beta, x, out);
}